// Round 3
// baseline (621.540 us; speedup 1.0000x reference)
//
#include <hip/hip_runtime.h>
#include <math.h>

#define BATCH   512
#define NSLOTS  65536
#define DIM     256

#define RB      64            // rows per block (simfused)
#define NROWG   (BATCH/RB)    // 8
#define NCG     64            // column groups (simfused)
#define CPG     (NSLOTS/NCG)  // 1024 slots per group
#define ST      32            // slot tile
#define NTILES  (CPG/ST)      // 32
#define DELTA   0.009f        // 2x worst-case bf16-input sim perturbation

// workspace layout (float offsets)
#define WS_QN   0
#define WS_RN   (WS_QN + BATCH*DIM)            // +131072
#define WS_WST  (WS_RN + NSLOTS)               // +65536
#define WS_DEN  (WS_WST + BATCH*4)             // +2048
#define WS_SST  (WS_DEN + BATCH)               // +512 : [512][64 cg][16 lanes][2] float2 = 8 MB
#define WS_VT   (WS_SST + BATCH*NCG*16*4)      // +2097152 : value^T bf16 [256 d][512 b] = 256 KB
#define WS_MN   (WS_VT + (BATCH*DIM)/2)        // +65536 : normalized-bf16 memory, chunk-swizzled, 32 MB
#define WS_MT   (WS_MN + ((size_t)NSLOTS*DIM)/2) // +8388608 : bf16 memory^T, chunk-swizzled, 32 MB
// WFT (wf^T bf16 [65536 slots][512 b] = 64 MB) aliases MN+MT (dead after k_simfused)
// total ~76.6 MB

typedef __attribute__((ext_vector_type(8))) short bf16x8;
typedef __attribute__((ext_vector_type(4))) float f32x4;

__device__ inline unsigned short f2b(float x){   // fp32 -> bf16 RNE
  unsigned u = __float_as_uint(x);
  unsigned r = u + 0x7FFFu + ((u >> 16) & 1u);
  return (unsigned short)(r >> 16);
}
__device__ inline float b2f(unsigned short b){
  return __uint_as_float(((unsigned)b) << 16);
}

__device__ __forceinline__ void gl16(const void* g, void* l){
  __builtin_amdgcn_global_load_lds(
      (__attribute__((address_space(1))) void*)g,
      (__attribute__((address_space(3))) void*)l, 16, 0, 0);
}

#define SBAR_LGKM() do{ asm volatile("s_waitcnt lgkmcnt(0)" ::: "memory"); \
                        __builtin_amdgcn_s_barrier();                      \
                        asm volatile("" ::: "memory"); }while(0)
#define SBAR_ALL()  do{ asm volatile("s_waitcnt vmcnt(0) lgkmcnt(0)" ::: "memory"); \
                        __builtin_amdgcn_s_barrier();                               \
                        asm volatile("" ::: "memory"); }while(0)

// ---------------- query L2 norm ----------------
__global__ __launch_bounds__(256) void k_qnorm(const float* __restrict__ q, float* __restrict__ qn){
  int b = blockIdx.x, t = threadIdx.x;
  float v = q[b*DIM + t];
  __shared__ float red[256];
  red[t] = v*v;
  __syncthreads();
  for (int s = 128; s > 0; s >>= 1){
    if (t < s) red[t] += red[t+s];
    __syncthreads();
  }
  float n = fmaxf(sqrtf(red[0]), 1e-12f);
  qn[b*DIM + t] = v / n;
}

// ---------------- prep: row norms + normalized-bf16 memory, chunk-swizzled ----------------
// MN_swz[s][chunk pos] : chunk c (8 dims, 16B) of slot s stored at position c ^ (s&7).
__global__ __launch_bounds__(256) void k_mnprep(const float* __restrict__ mem,
                                                float* __restrict__ rn,
                                                unsigned short* __restrict__ MN){
  __shared__ float rns[64];
  int t = threadIdx.x;
  int s0 = blockIdx.x * 64;
  int w = t >> 6, ln = t & 63;
  #pragma unroll
  for (int it = 0; it < 16; ++it){
    int r = it*4 + w;
    float4 v = ((const float4*)(mem + (size_t)(s0 + r)*DIM))[ln];
    float s = v.x*v.x + v.y*v.y + v.z*v.z + v.w*v.w;
    #pragma unroll
    for (int off = 32; off > 0; off >>= 1) s += __shfl_xor(s, off, 64);
    if (ln == 0){
      float inv = 1.0f / fmaxf(sqrtf(s), 1e-12f);
      rns[r] = inv; rn[s0 + r] = inv;
    }
  }
  __syncthreads();
  #pragma unroll
  for (int j = 0; j < 8; ++j){
    int id = j*256 + t;
    int r = id >> 5;        // local slot 0..63
    int c = id & 31;        // chunk 0..31
    float inv = rns[r];
    const float4* p = (const float4*)(mem + (size_t)(s0 + r)*DIM + c*8);
    float4 a = p[0], b = p[1];
    bf16x8 o;
    o[0]=(short)f2b(a.x*inv); o[1]=(short)f2b(a.y*inv); o[2]=(short)f2b(a.z*inv); o[3]=(short)f2b(a.w*inv);
    o[4]=(short)f2b(b.x*inv); o[5]=(short)f2b(b.y*inv); o[6]=(short)f2b(b.z*inv); o[7]=(short)f2b(b.w*inv);
    *(bf16x8*)&MN[(size_t)(s0 + r)*DIM + ((c ^ (r & 7))*8)] = o;
  }
}

// ---------------- prep: bf16 memory^T, chunk-swizzled ----------------
// MT_swz[d][...] : within each aligned 32-slot block, chunk p (8 slots) stored at p ^ ((d>>1)&3).
__global__ __launch_bounds__(256) void k_mtprep(const float* __restrict__ mem, unsigned short* __restrict__ MT){
  __shared__ __align__(16) unsigned short tile[64][68];
  int sb = (blockIdx.x >> 2)*64, dd = (blockIdx.x & 3)*64;
  int t = threadIdx.x;
  int w = t >> 6, ln = t & 63;
  #pragma unroll
  for (int k = 0; k < 4; ++k){
    int sl = w*16 + k*4 + (ln >> 4);
    int doff = (ln & 15)*4;
    float4 f = *(const float4*)&mem[(size_t)(sb + sl)*DIM + dd + doff];
    tile[doff+0][sl] = f2b(f.x);
    tile[doff+1][sl] = f2b(f.y);
    tile[doff+2][sl] = f2b(f.z);
    tile[doff+3][sl] = f2b(f.w);
  }
  __syncthreads();
  #pragma unroll
  for (int k = 0; k < 4; ++k){
    int dl = w*16 + k*4 + (ln >> 4);
    int boff = (ln & 15)*4;
    int B = boff >> 5;
    int p = (boff >> 3) & 3;
    int pp = p ^ ((dl >> 1) & 3);          // (d>>1)&3 == (dl>>1)&3 (dd % 64 == 0)
    int off = B*32 + pp*8 + (boff & 7);
    *(short4*)&MT[(size_t)(dd + dl)*NSLOTS + sb + off] = *(const short4*)&tile[dl][boff];
  }
}

// ---------------- value^T bf16 prep: VT[d][b] = bf16(value[b][d]) ----------------
__global__ __launch_bounds__(256) void k_prep(const float* __restrict__ val, unsigned short* __restrict__ VT){
  __shared__ __align__(16) unsigned short tile[64][68];
  int bb = (blockIdx.x >> 2)*64, dd = (blockIdx.x & 3)*64;
  int t = threadIdx.x;
  int w = t >> 6, ln = t & 63;
  #pragma unroll
  for (int k = 0; k < 4; ++k){
    int bl = w*16 + k*4 + (ln >> 4);
    int doff = (ln & 15)*4;
    float4 f = *(const float4*)&val[(size_t)(bb + bl)*DIM + dd + doff];
    tile[doff+0][bl] = f2b(f.x);
    tile[doff+1][bl] = f2b(f.y);
    tile[doff+2][bl] = f2b(f.z);
    tile[doff+3][bl] = f2b(f.w);
  }
  __syncthreads();
  #pragma unroll
  for (int k = 0; k < 4; ++k){
    int dl = w*16 + k*4 + (ln >> 4);
    int boff = (ln & 15)*4;
    *(short4*)&VT[(size_t)(dd + dl)*BATCH + bb + boff] = *(const short4*)&tile[dl][boff];
  }
}

// ---------------- per-row write-weight stats: {inv_denom, invZ} ----------------
__global__ __launch_bounds__(256) void k_wstats(const float* __restrict__ prev, const float* __restrict__ sw,
                                                float* __restrict__ wst){
  int b = blockIdx.x, t = threadIdx.x;
  float s0 = sw[0], s1 = sw[1], s2 = sw[2];
  const float* p = prev + (size_t)b*NSLOTS;
  const float4* p4 = (const float4*)p;
  __shared__ float rs[256];
  float lsum = 0.f;
  for (int i4 = t; i4 < NSLOTS/4; i4 += 256){
    float4 f = p4[i4];
    float lft = (i4 > 0) ? p[4*i4 - 1] : 0.f;
    float rgt = (i4 < NSLOTS/4 - 1) ? p[4*i4 + 4] : 0.f;
    float sh0 = s0*lft + s1*f.x + s2*f.y;
    float sh1 = s0*f.x + s1*f.y + s2*f.z;
    float sh2 = s0*f.y + s1*f.z + s2*f.w;
    float sh3 = s0*f.z + s1*f.w + s2*rgt;
    lsum += sh0*sqrtf(sh0) + sh1*sqrtf(sh1) + sh2*sqrtf(sh2) + sh3*sqrtf(sh3);
  }
  rs[t] = lsum;
  __syncthreads();
  for (int s = 128; s > 0; s >>= 1){
    if (t < s) rs[t] += rs[t+s];
    __syncthreads();
  }
  float inv_d = 1.0f / (rs[0] + 1e-8f);
  __syncthreads();
  float lz = 0.f;
  for (int i4 = t; i4 < NSLOTS/4; i4 += 256){
    float4 f = p4[i4];
    float lft = (i4 > 0) ? p[4*i4 - 1] : 0.f;
    float rgt = (i4 < NSLOTS/4 - 1) ? p[4*i4 + 4] : 0.f;
    float sh0 = s0*lft + s1*f.x + s2*f.y;
    float sh1 = s0*f.x + s1*f.y + s2*f.z;
    float sh2 = s0*f.y + s1*f.z + s2*f.w;
    float sh3 = s0*f.z + s1*f.w + s2*rgt;
    lz += __expf(sh0*sqrtf(sh0)*inv_d) + __expf(sh1*sqrtf(sh1)*inv_d)
        + __expf(sh2*sqrtf(sh2)*inv_d) + __expf(sh3*sqrtf(sh3)*inv_d);
  }
  rs[t] = lz;
  __syncthreads();
  for (int s = 128; s > 0; s >>= 1){
    if (t < s) rs[t] += rs[t+s];
    __syncthreads();
  }
  if (t == 0){
    float4 o; o.x = inv_d; o.y = 1.0f/rs[0]; o.z = 0.f; o.w = 0.f;
    ((float4*)wst)[b] = o;
  }
}

// ---------------- wf transpose: WFT[slot][b] = bf16(wf[b][slot]) ----------------
// Reads prev batch-major (coalesced), computes wf, LDS-transposes 64x64 tiles,
// writes slot-major bf16 in 128B-contiguous granules. Fixes the DRAM page-thrash
// of newmem's former 256KB-strided prev reads.
__global__ __launch_bounds__(256) void k_wft(const float* __restrict__ prev, const float* __restrict__ sw,
                                             const float* __restrict__ wst, unsigned short* __restrict__ WFT){
  __shared__ __align__(16) unsigned short T[64][72];
  int bs = ((int)blockIdx.x & 7) * 64;       // batch tile
  int ss = ((int)blockIdx.x >> 3) * 64;      // slot tile
  int t = threadIdx.x;
  float s0 = sw[0], s1 = sw[1], s2 = sw[2];
  int rr = t >> 4;          // 0..15 batch row within pass
  int cc = t & 15;          // float4 col (slot dim)
  #pragma unroll
  for (int pass = 0; pass < 4; ++pass){
    int bl = pass*16 + rr;
    int b = bs + bl;
    const float* p = prev + (size_t)b*NSLOTS + ss;
    float2 st = *(const float2*)&wst[b*4];   // {inv_d, invZ}
    int s = cc*4;
    float4 f = *(const float4*)(p + s);
    int gs = ss + s;
    float lft = (gs > 0) ? p[s-1] : 0.f;
    float rgt = (gs + 4 < NSLOTS) ? p[s+4] : 0.f;
    float sh0 = s0*lft + s1*f.x + s2*f.y;
    float sh1 = s0*f.x + s1*f.y + s2*f.z;
    float sh2 = s0*f.y + s1*f.z + s2*f.w;
    float sh3 = s0*f.z + s1*f.w + s2*rgt;
    T[s+0][bl] = f2b(__expf(sh0*sqrtf(sh0)*st.x)*st.y);
    T[s+1][bl] = f2b(__expf(sh1*sqrtf(sh1)*st.x)*st.y);
    T[s+2][bl] = f2b(__expf(sh2*sqrtf(sh2)*st.x)*st.y);
    T[s+3][bl] = f2b(__expf(sh3*sqrtf(sh3)*st.x)*st.y);
  }
  __syncthreads();
  int sr = t >> 3;          // 0..31 slot row
  int ch = t & 7;           // 16B chunk within the 128B row
  #pragma unroll
  for (int k = 0; k < 2; ++k){
    int row = k*32 + sr;
    *(bf16x8*)&WFT[(size_t)(ss + row)*BATCH + bs + ch*8] = *(const bf16x8*)&T[row][ch*8];
  }
}

// ---------------- MFMA fused sim pass: async-staged, double-buffered, swizzled LDS ----------------
// Ms LDS [32][256] bf16 linear; content pre-swizzled in MN (chunk c at c^(row&7)).
// Md LDS [256][32] bf16 linear; content pre-swizzled in MT (chunk p at p^((d>>1)&3)).
__global__ __launch_bounds__(256, 2) void k_simfused(
    const float* __restrict__ qn,
    const unsigned short* __restrict__ MN,
    const unsigned short* __restrict__ MT,
    float* __restrict__ outc, float* __restrict__ denom, float* __restrict__ sst)
{
  __shared__ __align__(16) unsigned short Ms[2][32*256];
  __shared__ __align__(16) unsigned short Md[2][256*32];
  __shared__ __align__(16) unsigned short Plds[64*40];

  int cg = blockIdx.x, rg = blockIdx.y;     // swapped grid: same-cg blocks share an XCD L2
  int t = threadIdx.x;
  int w = t >> 6;
  int lane = t & 63;
  int l = lane & 15;
  int q = lane >> 4;
  int row0 = rg * RB;

  bf16x8 qa[8];
  {
    int qrow = row0 + 16*w + l;
    #pragma unroll
    for (int kk = 0; kk < 8; ++kk){
      const float4* qp = (const float4*)&qn[(size_t)qrow*DIM + 32*kk + 8*q];
      float4 a0 = qp[0], a1 = qp[1];
      bf16x8 v;
      v[0]=(short)f2b(a0.x); v[1]=(short)f2b(a0.y); v[2]=(short)f2b(a0.z); v[3]=(short)f2b(a0.w);
      v[4]=(short)f2b(a1.x); v[5]=(short)f2b(a1.y); v[6]=(short)f2b(a1.z); v[7]=(short)f2b(a1.w);
      qa[kk] = v;
    }
  }

  // per-lane staging source bases (tile 0)
  const char* msP = (const char*)MN + (size_t)cg*CPG*512 + (size_t)w*4096 + (size_t)lane*16;
  const char* mtP = (const char*)MT + (size_t)(w*64 + (lane>>2))*((size_t)NSLOTS*2)
                                    + (size_t)cg*CPG*2 + (size_t)(lane&3)*16;

  auto STAGE = [&](int tl, int buf){
    size_t mso = (size_t)tl*16384;   // 32 rows * 512 B
    size_t mto = (size_t)tl*64;      // 32 slots * 2 B
    #pragma unroll
    for (int j = 0; j < 4; ++j)
      gl16(msP + mso + (size_t)j*1024, &Ms[buf][w*2048 + j*512]);
    #pragma unroll
    for (int j = 0; j < 4; ++j)
      gl16(mtP + mto + (size_t)j*2097152, &Md[buf][w*2048 + j*512]);
  };

  f32x4 accO[16];
  #pragma unroll
  for (int c = 0; c < 16; ++c) accO[c] = (f32x4){0.f,0.f,0.f,0.f};

  float dsum[4] = {0.f,0.f,0.f,0.f};
  float tv0[4] = {-1e30f,-1e30f,-1e30f,-1e30f}, tv1[4] = {-1e30f,-1e30f,-1e30f,-1e30f};
  int   ti0[4] = {0,0,0,0}, ti1[4] = {0,0,0,0};

  STAGE(0, 0);
  SBAR_ALL();

  int r7 = l & 7;
  int sw2 = (q ^ ((l >> 1) & 3)) * 8;

  for (int tile = 0; tile < NTILES; ++tile){
    int cur = tile & 1;
    if (tile + 1 < NTILES) STAGE(tile + 1, cur ^ 1);
    int i0 = cg*CPG + tile*ST;

    // ---- QK^T on Ms[cur] ----
    const unsigned short* msb = &Ms[cur][0];
    f32x4 S0 = (f32x4){0.f,0.f,0.f,0.f}, S1 = (f32x4){0.f,0.f,0.f,0.f};
    #pragma unroll
    for (int kk = 0; kk < 8; ++kk){
      int c0 = ((4*kk + q) ^ r7) * 8;
      bf16x8 b0 = *(const bf16x8*)&msb[(l     )*256 + c0];
      bf16x8 b1 = *(const bf16x8*)&msb[(16 + l)*256 + c0];
      S0 = __builtin_amdgcn_mfma_f32_16x16x32_bf16(qa[kk], b0, S0, 0, 0, 0);
      S1 = __builtin_amdgcn_mfma_f32_16x16x32_bf16(qa[kk], b1, S1, 0, 0, 0);
    }

    // ---- exp / top-2 track / stage P ----
    #pragma unroll
    for (int c = 0; c < 2; ++c){
      int slot = i0 + 16*c + l;
      #pragma unroll
      for (int reg = 0; reg < 4; ++reg){
        float v = (c == 0) ? S0[reg] : S1[reg];
        bool g0 = v > tv0[reg];
        bool g1 = v > tv1[reg];
        float ov0 = tv0[reg]; int oi0 = ti0[reg];
        tv1[reg] = g0 ? ov0 : (g1 ? v : tv1[reg]);
        ti1[reg] = g0 ? oi0 : (g1 ? slot : ti1[reg]);
        tv0[reg] = g0 ? v : tv0[reg];
        ti0[reg] = g0 ? slot : ti0[reg];
        unsigned short wb = f2b(__expf(v));
        dsum[reg] += b2f(wb);
        Plds[(16*w + 4*q + reg)*40 + 16*c + l] = (short)wb;
      }
    }
    SBAR_LGKM();   // P visible to all waves; staging loads stay in flight

    // ---- PV on Md[cur] ----
    bf16x8 pa = *(const bf16x8*)&Plds[(16*w + l)*40 + 8*q];
    const unsigned short* mdb = &Md[cur][0];
    #pragma unroll
    for (int ct = 0; ct < 16; ++ct){
      bf16x8 b = *(const bf16x8*)&mdb[(16*ct + l)*32 + sw2];
      accO[ct] = __builtin_amdgcn_mfma_f32_16x16x32_bf16(pa, b, accO[ct], 0, 0, 0);
    }
    SBAR_ALL();    // next tile's staging complete everywhere; P reads done
  }

  #pragma unroll
  for (int reg = 0; reg < 4; ++reg){
    float s = dsum[reg];
    s += __shfl_xor(s, 1, 64); s += __shfl_xor(s, 2, 64);
    s += __shfl_xor(s, 4, 64); s += __shfl_xor(s, 8, 64);
    if (l == 0) atomicAdd(&denom[row0 + 16*w + 4*q + reg], s);
  }
  #pragma unroll
  for (int reg = 0; reg < 4; ++reg){
    int row = row0 + 16*w + 4*q + reg;
    size_t base = (((size_t)row*NCG + cg)*16 + l)*2;
    float2* S2 = (float2*)sst;
    S2[base + 0] = make_float2(tv0[reg], __int_as_float(ti0[reg]));
    S2[base + 1] = make_float2(tv1[reg], __int_as_float(ti1[reg]));
  }
  #pragma unroll
  for (int ct = 0; ct < 16; ++ct){
    #pragma unroll
    for (int reg = 0; reg < 4; ++reg){
      int row = row0 + 16*w + 4*q + reg;
      atomicAdd(&outc[(size_t)row*DIM + 16*ct + l], accO[ct][reg]);
    }
  }
}

// ---------------- finish: exact-fp32 argmax recheck + normalize + topk gather ----------------
__global__ __launch_bounds__(256) void k_finish(const float* __restrict__ sst, const float* __restrict__ denom,
                                                const float* __restrict__ qn, const float* __restrict__ rn,
                                                const float* __restrict__ mem,
                                                float* __restrict__ outc, float* __restrict__ outk){
  int row = blockIdx.x, t = threadIdx.x;
  __shared__ float red[256];
  __shared__ int cnt;
  __shared__ int cidx[128];
  __shared__ float csim[128];
  __shared__ int bestIdx;
  const float2* S = (const float2*)sst + (size_t)row*NCG*16*2;
  float2 e[8];
  float lmax = -1e30f;
  #pragma unroll
  for (int k = 0; k < 8; ++k){ e[k] = S[t*8 + k]; lmax = fmaxf(lmax, e[k].x); }
  red[t] = lmax;
  __syncthreads();
  for (int s = 128; s > 0; s >>= 1){
    if (t < s) red[t] = fmaxf(red[t], red[t+s]);
    __syncthreads();
  }
  float M = red[0];
  if (t == 0) cnt = 0;
  __syncthreads();
  #pragma unroll
  for (int k = 0; k < 8; ++k){
    if (e[k].x >= M - DELTA){
      int p = atomicAdd(&cnt, 1);
      if (p < 128) cidx[p] = __float_as_int(e[k].y);
    }
  }
  __syncthreads();
  int n = min(cnt, 128);
  int wv = t >> 6, ln = t & 63;
  for (int ci = wv; ci < n; ci += 4){
    int slot = cidx[ci];
    float4 a = ((const float4*)&qn[(size_t)row*DIM])[ln];
    float4 b = ((const float4*)&mem[(size_t)slot*DIM])[ln];
    float s = a.x*b.x + a.y*b.y + a.z*b.z + a.w*b.w;
    #pragma unroll
    for (int off = 32; off > 0; off >>= 1) s += __shfl_xor(s, off, 64);
    if (ln == 0) csim[ci] = s * rn[slot];
  }
  __syncthreads();
  if (t == 0){
    float bv = -1e30f; int bi = 0x7fffffff;
    for (int i = 0; i < n; ++i){
      float v = csim[i]; int id = cidx[i];
      if (v > bv || (v == bv && id < bi)){ bv = v; bi = id; }
    }
    bestIdx = bi;
  }
  __syncthreads();
  float inv = 1.0f / denom[row];
  outc[(size_t)row*DIM + t] *= inv;
  outk[(size_t)row*DIM + t] = mem[(size_t)bestIdx*DIM + t];
}

// ---------------- new_mem via MFMA: out = mem*erase + W^T @ value ----------------
// A-fragments load straight from WFT (slot-major bf16, fully coalesced);
// erase product recomputed from the bf16 wf in-register (err ~1e-6 abs).
// No prev access, no exp, no LDS, no barriers.
__global__ __launch_bounds__(256, 4) void k_newmem(const float* __restrict__ mem,
                                                const unsigned short* __restrict__ VT,
                                                const unsigned short* __restrict__ WFT,
                                                float* __restrict__ outm){
  int t = threadIdx.x;
  int i0 = blockIdx.x * 64;
  int w = t >> 6;
  int lane = t & 63;
  int l = lane & 15, q = lane >> 4;
  int slot = i0 + 16*w + l;          // this thread's A-row (global slot)

  f32x4 accO[16];
  #pragma unroll
  for (int c = 0; c < 16; ++c) accO[c] = (f32x4){0.f,0.f,0.f,0.f};
  float epl = 1.0f;

  const unsigned short* wrow = WFT + (size_t)slot*BATCH;

  #pragma unroll 2
  for (int c = 0; c < 16; ++c){
    bf16x8 af = *(const bf16x8*)&wrow[c*32 + 8*q];
    #pragma unroll
    for (int j = 0; j < 8; ++j)
      epl *= (1.0f - 0.5f*b2f((unsigned short)af[j]));
    #pragma unroll
    for (int ct = 0; ct < 16; ++ct){
      bf16x8 bfg = *(const bf16x8*)&VT[(size_t)(16*ct + l)*BATCH + c*32 + 8*q];
      accO[ct] = __builtin_amdgcn_mfma_f32_16x16x32_bf16(af, bfg, accO[ct], 0, 0, 0);
    }
  }

  // complete erase product across the 4 q-groups (same l => same slot)
  epl *= __shfl_xor(epl, 16, 64);
  epl *= __shfl_xor(epl, 32, 64);

  #pragma unroll
  for (int reg = 0; reg < 4; ++reg){
    int so = i0 + 16*w + 4*q + reg;
    float e = __shfl(epl, 4*q + reg, 64);   // lane (l'=4q+reg, q'=0) holds it
    #pragma unroll
    for (int ct = 0; ct < 16; ++ct){
      int d = 16*ct + l;
      outm[(size_t)so*DIM + d] = mem[(size_t)so*DIM + d]*e + accO[ct][reg];
    }
  }
}

extern "C" void kernel_launch(void* const* d_in, const int* in_sizes, int n_in,
                              void* d_out, int out_size, void* d_ws, size_t ws_size,
                              hipStream_t stream){
  const float* mem  = (const float*)d_in[0];
  const float* qry  = (const float*)d_in[1];
  const float* val  = (const float*)d_in[2];
  const float* prev = (const float*)d_in[3];
  const float* sw   = (const float*)d_in[4];
  // d_in[5] = k : unused — w_topk is analytically one-hot at argmax(sim) for any k
  float* out = (float*)d_out;
  float* ws  = (float*)d_ws;

  float* qn   = ws + WS_QN;
  float* rn   = ws + WS_RN;
  float* wst  = ws + WS_WST;
  float* den  = ws + WS_DEN;
  float* sst  = ws + WS_SST;
  unsigned short* VT = (unsigned short*)(ws + WS_VT);
  unsigned short* MN = (unsigned short*)(ws + WS_MN);
  unsigned short* MT = (unsigned short*)(ws + WS_MT);
  unsigned short* WFT = MN;   // aliases MN+MT (64 MB), dead after k_simfused

  float* out_content = out;
  float* out_topk    = out + BATCH*DIM;
  float* out_newmem  = out + 2*BATCH*DIM;

  hipMemsetAsync(out_content, 0, BATCH*DIM*sizeof(float), stream);
  hipMemsetAsync(den, 0, BATCH*sizeof(float), stream);
  hipLaunchKernelGGL(k_qnorm,   dim3(BATCH),       dim3(DIM), 0, stream, qry, qn);
  hipLaunchKernelGGL(k_mnprep,  dim3(NSLOTS/64),   dim3(256), 0, stream, mem, rn, MN);
  hipLaunchKernelGGL(k_mtprep,  dim3((NSLOTS/64)*4), dim3(256), 0, stream, mem, MT);
  hipLaunchKernelGGL(k_prep,    dim3(32),          dim3(256), 0, stream, val, VT);
  hipLaunchKernelGGL(k_wstats,  dim3(BATCH),       dim3(256), 0, stream, prev, sw, wst);
  hipLaunchKernelGGL(k_simfused,dim3(NCG, NROWG),  dim3(256), 0, stream, qn, MN, MT, out_content, den, sst);
  hipLaunchKernelGGL(k_wft,     dim3((NSLOTS/64)*(BATCH/64)), dim3(256), 0, stream, prev, sw, wst, WFT);
  hipLaunchKernelGGL(k_finish,  dim3(BATCH),       dim3(256), 0, stream, sst, den, qn, rn, mem, out_content, out_topk);
  hipLaunchKernelGGL(k_newmem,  dim3(NSLOTS/64),   dim3(256), 0, stream, mem, VT, WFT, out_newmem);
}

// Round 4
// 522.631 us; speedup vs baseline: 1.1893x; 1.1893x over previous
//
#include <hip/hip_runtime.h>
#include <math.h>

#define BATCH   512
#define NSLOTS  65536
#define DIM     256

#define RB      64            // rows per block (simfused)
#define NROWG   (BATCH/RB)    // 8
#define NCG     64            // column groups (simfused)
#define CPG     (NSLOTS/NCG)  // 1024 slots per group
#define ST      32            // slot tile
#define NTILES  (CPG/ST)      // 32
#define DELTA   0.009f        // 2x worst-case bf16-input sim perturbation

// workspace layout (float offsets)
#define WS_QN   0
#define WS_RN   (WS_QN + BATCH*DIM)            // +131072
#define WS_WST  (WS_RN + NSLOTS)               // +65536
#define WS_DEN  (WS_WST + BATCH*4)             // +2048
#define WS_SST  (WS_DEN + BATCH)               // +512 : [512][64 cg][16 lanes][2] float2 = 8 MB
#define WS_VT   (WS_SST + BATCH*NCG*16*4)      // +2097152 : value^T bf16, chunked [16 c][256 d][32 b], 256 KB
#define WS_MN   (WS_VT + (BATCH*DIM)/2)        // +65536 : normalized-bf16 memory, chunk-swizzled, 32 MB
#define WS_MT   (WS_MN + ((size_t)NSLOTS*DIM)/2) // +8388608 : bf16 memory^T, chunk-swizzled, 32 MB
// WFT2 (wf bf16 [1024 sblk][16 c][64 s][32 b] = 64 MB) aliases MN+MT (dead after k_simfused)
// total ~76.6 MB

typedef __attribute__((ext_vector_type(8))) short bf16x8;
typedef __attribute__((ext_vector_type(4))) float f32x4;

__device__ inline unsigned short f2b(float x){   // fp32 -> bf16 RNE
  unsigned u = __float_as_uint(x);
  unsigned r = u + 0x7FFFu + ((u >> 16) & 1u);
  return (unsigned short)(r >> 16);
}
__device__ inline float b2f(unsigned short b){
  return __uint_as_float(((unsigned)b) << 16);
}

__device__ __forceinline__ void gl16(const void* g, void* l){
  __builtin_amdgcn_global_load_lds(
      (__attribute__((address_space(1))) void*)g,
      (__attribute__((address_space(3))) void*)l, 16, 0, 0);
}

#define SBAR_LGKM() do{ asm volatile("s_waitcnt lgkmcnt(0)" ::: "memory"); \
                        __builtin_amdgcn_s_barrier();                      \
                        asm volatile("" ::: "memory"); }while(0)
#define SBAR_ALL()  do{ asm volatile("s_waitcnt vmcnt(0) lgkmcnt(0)" ::: "memory"); \
                        __builtin_amdgcn_s_barrier();                               \
                        asm volatile("" ::: "memory"); }while(0)

// ---------------- query L2 norm ----------------
__global__ __launch_bounds__(256) void k_qnorm(const float* __restrict__ q, float* __restrict__ qn){
  int b = blockIdx.x, t = threadIdx.x;
  float v = q[b*DIM + t];
  __shared__ float red[256];
  red[t] = v*v;
  __syncthreads();
  for (int s = 128; s > 0; s >>= 1){
    if (t < s) red[t] += red[t+s];
    __syncthreads();
  }
  float n = fmaxf(sqrtf(red[0]), 1e-12f);
  qn[b*DIM + t] = v / n;
}

// ---------------- prep: row norms + normalized-bf16 memory, chunk-swizzled ----------------
// MN_swz[s][chunk pos] : chunk c (8 dims, 16B) of slot s stored at position c ^ (s&7).
__global__ __launch_bounds__(256) void k_mnprep(const float* __restrict__ mem,
                                                float* __restrict__ rn,
                                                unsigned short* __restrict__ MN){
  __shared__ float rns[64];
  int t = threadIdx.x;
  int s0 = blockIdx.x * 64;
  int w = t >> 6, ln = t & 63;
  #pragma unroll
  for (int it = 0; it < 16; ++it){
    int r = it*4 + w;
    float4 v = ((const float4*)(mem + (size_t)(s0 + r)*DIM))[ln];
    float s = v.x*v.x + v.y*v.y + v.z*v.z + v.w*v.w;
    #pragma unroll
    for (int off = 32; off > 0; off >>= 1) s += __shfl_xor(s, off, 64);
    if (ln == 0){
      float inv = 1.0f / fmaxf(sqrtf(s), 1e-12f);
      rns[r] = inv; rn[s0 + r] = inv;
    }
  }
  __syncthreads();
  #pragma unroll
  for (int j = 0; j < 8; ++j){
    int id = j*256 + t;
    int r = id >> 5;        // local slot 0..63
    int c = id & 31;        // chunk 0..31
    float inv = rns[r];
    const float4* p = (const float4*)(mem + (size_t)(s0 + r)*DIM + c*8);
    float4 a = p[0], b = p[1];
    bf16x8 o;
    o[0]=(short)f2b(a.x*inv); o[1]=(short)f2b(a.y*inv); o[2]=(short)f2b(a.z*inv); o[3]=(short)f2b(a.w*inv);
    o[4]=(short)f2b(b.x*inv); o[5]=(short)f2b(b.y*inv); o[6]=(short)f2b(b.z*inv); o[7]=(short)f2b(b.w*inv);
    *(bf16x8*)&MN[(size_t)(s0 + r)*DIM + ((c ^ (r & 7))*8)] = o;
  }
}

// ---------------- prep: bf16 memory^T, chunk-swizzled ----------------
// MT_swz[d][...] : within each aligned 32-slot block, chunk p (8 slots) stored at p ^ ((d>>1)&3).
__global__ __launch_bounds__(256) void k_mtprep(const float* __restrict__ mem, unsigned short* __restrict__ MT){
  __shared__ __align__(16) unsigned short tile[64][68];
  int sb = (blockIdx.x >> 2)*64, dd = (blockIdx.x & 3)*64;
  int t = threadIdx.x;
  int w = t >> 6, ln = t & 63;
  #pragma unroll
  for (int k = 0; k < 4; ++k){
    int sl = w*16 + k*4 + (ln >> 4);
    int doff = (ln & 15)*4;
    float4 f = *(const float4*)&mem[(size_t)(sb + sl)*DIM + dd + doff];
    tile[doff+0][sl] = f2b(f.x);
    tile[doff+1][sl] = f2b(f.y);
    tile[doff+2][sl] = f2b(f.z);
    tile[doff+3][sl] = f2b(f.w);
  }
  __syncthreads();
  #pragma unroll
  for (int k = 0; k < 4; ++k){
    int dl = w*16 + k*4 + (ln >> 4);
    int boff = (ln & 15)*4;
    int B = boff >> 5;
    int p = (boff >> 3) & 3;
    int pp = p ^ ((dl >> 1) & 3);          // (d>>1)&3 == (dl>>1)&3 (dd % 64 == 0)
    int off = B*32 + pp*8 + (boff & 7);
    *(short4*)&MT[(size_t)(dd + dl)*NSLOTS + sb + off] = *(const short4*)&tile[dl][boff];
  }
}

// ---------------- value^T bf16 prep: VT2[c][d][b-local], swizzled ----------------
// Chunk c (32 batches) stored contiguously (16 KB); within it row d, 8-batch
// group p stored at p ^ ((d>>1)&3)  — matches k_newmem's LDS B-frag read.
__global__ __launch_bounds__(256) void k_prep(const float* __restrict__ val, unsigned short* __restrict__ VT){
  __shared__ __align__(16) unsigned short tile[64][68];
  int bb = (blockIdx.x >> 2)*64, dd = (blockIdx.x & 3)*64;
  int t = threadIdx.x;
  int w = t >> 6, ln = t & 63;
  #pragma unroll
  for (int k = 0; k < 4; ++k){
    int bl = w*16 + k*4 + (ln >> 4);
    int doff = (ln & 15)*4;
    float4 f = *(const float4*)&val[(size_t)(bb + bl)*DIM + dd + doff];
    tile[doff+0][bl] = f2b(f.x);
    tile[doff+1][bl] = f2b(f.y);
    tile[doff+2][bl] = f2b(f.z);
    tile[doff+3][bl] = f2b(f.w);
  }
  __syncthreads();
  #pragma unroll
  for (int k = 0; k < 4; ++k){
    int dl = w*16 + k*4 + (ln >> 4);
    int boff = (ln & 15)*4;
    int c  = (bb + boff) >> 5;
    int p  = (boff >> 3) & 3;
    int pp = p ^ ((dl >> 1) & 3);
    size_t addr = (size_t)c*8192 + (size_t)(dd + dl)*32 + pp*8 + (boff & 7);
    *(short4*)&VT[addr] = *(const short4*)&tile[dl][boff];
  }
}

// ---------------- per-row write-weight stats: {inv_denom, invZ} ----------------
__global__ __launch_bounds__(256) void k_wstats(const float* __restrict__ prev, const float* __restrict__ sw,
                                                float* __restrict__ wst){
  int b = blockIdx.x, t = threadIdx.x;
  float s0 = sw[0], s1 = sw[1], s2 = sw[2];
  const float* p = prev + (size_t)b*NSLOTS;
  const float4* p4 = (const float4*)p;
  __shared__ float rs[256];
  float lsum = 0.f;
  for (int i4 = t; i4 < NSLOTS/4; i4 += 256){
    float4 f = p4[i4];
    float lft = (i4 > 0) ? p[4*i4 - 1] : 0.f;
    float rgt = (i4 < NSLOTS/4 - 1) ? p[4*i4 + 4] : 0.f;
    float sh0 = s0*lft + s1*f.x + s2*f.y;
    float sh1 = s0*f.x + s1*f.y + s2*f.z;
    float sh2 = s0*f.y + s1*f.z + s2*f.w;
    float sh3 = s0*f.z + s1*f.w + s2*rgt;
    lsum += sh0*sqrtf(sh0) + sh1*sqrtf(sh1) + sh2*sqrtf(sh2) + sh3*sqrtf(sh3);
  }
  rs[t] = lsum;
  __syncthreads();
  for (int s = 128; s > 0; s >>= 1){
    if (t < s) rs[t] += rs[t+s];
    __syncthreads();
  }
  float inv_d = 1.0f / (rs[0] + 1e-8f);
  __syncthreads();
  float lz = 0.f;
  for (int i4 = t; i4 < NSLOTS/4; i4 += 256){
    float4 f = p4[i4];
    float lft = (i4 > 0) ? p[4*i4 - 1] : 0.f;
    float rgt = (i4 < NSLOTS/4 - 1) ? p[4*i4 + 4] : 0.f;
    float sh0 = s0*lft + s1*f.x + s2*f.y;
    float sh1 = s0*f.x + s1*f.y + s2*f.z;
    float sh2 = s0*f.y + s1*f.z + s2*f.w;
    float sh3 = s0*f.z + s1*f.w + s2*rgt;
    lz += __expf(sh0*sqrtf(sh0)*inv_d) + __expf(sh1*sqrtf(sh1)*inv_d)
        + __expf(sh2*sqrtf(sh2)*inv_d) + __expf(sh3*sqrtf(sh3)*inv_d);
  }
  rs[t] = lz;
  __syncthreads();
  for (int s = 128; s > 0; s >>= 1){
    if (t < s) rs[t] += rs[t+s];
    __syncthreads();
  }
  if (t == 0){
    float4 o; o.x = inv_d; o.y = 1.0f/rs[0]; o.z = 0.f; o.w = 0.f;
    ((float4*)wst)[b] = o;
  }
}

// ---------------- wf: WFT2[sblk][c][slot-local][b-local], swizzled ----------------
// Reads prev batch-major (coalesced), computes wf, LDS-transposes 64x64 tiles,
// writes the tiled layout k_newmem stages from: slot tile sblk, batch chunk c
// (32 b) contiguous 4 KB; within it row s, 8-batch group p at p ^ ((s>>1)&3).
__global__ __launch_bounds__(256) void k_wft(const float* __restrict__ prev, const float* __restrict__ sw,
                                             const float* __restrict__ wst, unsigned short* __restrict__ WFT){
  __shared__ __align__(16) unsigned short T[64][72];
  int bs = ((int)blockIdx.x & 7) * 64;       // batch tile
  int ss = ((int)blockIdx.x >> 3) * 64;      // slot tile
  int t = threadIdx.x;
  float s0 = sw[0], s1 = sw[1], s2 = sw[2];
  int rr = t >> 4;          // 0..15 batch row within pass
  int cc = t & 15;          // float4 col (slot dim)
  #pragma unroll
  for (int pass = 0; pass < 4; ++pass){
    int bl = pass*16 + rr;
    int b = bs + bl;
    const float* p = prev + (size_t)b*NSLOTS + ss;
    float2 st = *(const float2*)&wst[b*4];   // {inv_d, invZ}
    int s = cc*4;
    float4 f = *(const float4*)(p + s);
    int gs = ss + s;
    float lft = (gs > 0) ? p[s-1] : 0.f;
    float rgt = (gs + 4 < NSLOTS) ? p[s+4] : 0.f;
    float sh0 = s0*lft + s1*f.x + s2*f.y;
    float sh1 = s0*f.x + s1*f.y + s2*f.z;
    float sh2 = s0*f.y + s1*f.z + s2*f.w;
    float sh3 = s0*f.z + s1*f.w + s2*rgt;
    T[s+0][bl] = f2b(__expf(sh0*sqrtf(sh0)*st.x)*st.y);
    T[s+1][bl] = f2b(__expf(sh1*sqrtf(sh1)*st.x)*st.y);
    T[s+2][bl] = f2b(__expf(sh2*sqrtf(sh2)*st.x)*st.y);
    T[s+3][bl] = f2b(__expf(sh3*sqrtf(sh3)*st.x)*st.y);
  }
  __syncthreads();
  int sr = t >> 3;          // 0..31 slot row
  int ch = t & 7;           // 16B chunk within the 128B row (= 8 batches)
  #pragma unroll
  for (int k = 0; k < 2; ++k){
    int row = k*32 + sr;
    int c  = (bs >> 5) + (ch >> 2);          // global 32-batch chunk
    int pp = (ch & 3) ^ ((row >> 1) & 3);
    size_t addr = (size_t)(ss >> 6)*32768 + (size_t)c*2048 + (size_t)row*32 + pp*8;
    *(bf16x8*)&WFT[addr] = *(const bf16x8*)&T[row][ch*8];
  }
}

// ---------------- MFMA fused sim pass: async-staged, double-buffered, swizzled LDS ----------------
// Ms LDS [32][256] bf16 linear; content pre-swizzled in MN (chunk c at c^(row&7)).
// Md LDS [256][32] bf16 linear; content pre-swizzled in MT (chunk p at p^((d>>1)&3)).
__global__ __launch_bounds__(256, 2) void k_simfused(
    const float* __restrict__ qn,
    const unsigned short* __restrict__ MN,
    const unsigned short* __restrict__ MT,
    float* __restrict__ outc, float* __restrict__ denom, float* __restrict__ sst)
{
  __shared__ __align__(16) unsigned short Ms[2][32*256];
  __shared__ __align__(16) unsigned short Md[2][256*32];
  __shared__ __align__(16) unsigned short Plds[64*40];

  int cg = blockIdx.x, rg = blockIdx.y;     // swapped grid: same-cg blocks share an XCD L2
  int t = threadIdx.x;
  int w = t >> 6;
  int lane = t & 63;
  int l = lane & 15;
  int q = lane >> 4;
  int row0 = rg * RB;

  bf16x8 qa[8];
  {
    int qrow = row0 + 16*w + l;
    #pragma unroll
    for (int kk = 0; kk < 8; ++kk){
      const float4* qp = (const float4*)&qn[(size_t)qrow*DIM + 32*kk + 8*q];
      float4 a0 = qp[0], a1 = qp[1];
      bf16x8 v;
      v[0]=(short)f2b(a0.x); v[1]=(short)f2b(a0.y); v[2]=(short)f2b(a0.z); v[3]=(short)f2b(a0.w);
      v[4]=(short)f2b(a1.x); v[5]=(short)f2b(a1.y); v[6]=(short)f2b(a1.z); v[7]=(short)f2b(a1.w);
      qa[kk] = v;
    }
  }

  // per-lane staging source bases (tile 0)
  const char* msP = (const char*)MN + (size_t)cg*CPG*512 + (size_t)w*4096 + (size_t)lane*16;
  const char* mtP = (const char*)MT + (size_t)(w*64 + (lane>>2))*((size_t)NSLOTS*2)
                                    + (size_t)cg*CPG*2 + (size_t)(lane&3)*16;

  auto STAGE = [&](int tl, int buf){
    size_t mso = (size_t)tl*16384;   // 32 rows * 512 B
    size_t mto = (size_t)tl*64;      // 32 slots * 2 B
    #pragma unroll
    for (int j = 0; j < 4; ++j)
      gl16(msP + mso + (size_t)j*1024, &Ms[buf][w*2048 + j*512]);
    #pragma unroll
    for (int j = 0; j < 4; ++j)
      gl16(mtP + mto + (size_t)j*2097152, &Md[buf][w*2048 + j*512]);
  };

  f32x4 accO[16];
  #pragma unroll
  for (int c = 0; c < 16; ++c) accO[c] = (f32x4){0.f,0.f,0.f,0.f};

  float dsum[4] = {0.f,0.f,0.f,0.f};
  float tv0[4] = {-1e30f,-1e30f,-1e30f,-1e30f}, tv1[4] = {-1e30f,-1e30f,-1e30f,-1e30f};
  int   ti0[4] = {0,0,0,0}, ti1[4] = {0,0,0,0};

  STAGE(0, 0);
  SBAR_ALL();

  int r7 = l & 7;
  int sw2 = (q ^ ((l >> 1) & 3)) * 8;

  for (int tile = 0; tile < NTILES; ++tile){
    int cur = tile & 1;
    if (tile + 1 < NTILES) STAGE(tile + 1, cur ^ 1);
    int i0 = cg*CPG + tile*ST;

    // ---- QK^T on Ms[cur] ----
    const unsigned short* msb = &Ms[cur][0];
    f32x4 S0 = (f32x4){0.f,0.f,0.f,0.f}, S1 = (f32x4){0.f,0.f,0.f,0.f};
    #pragma unroll
    for (int kk = 0; kk < 8; ++kk){
      int c0 = ((4*kk + q) ^ r7) * 8;
      bf16x8 b0 = *(const bf16x8*)&msb[(l     )*256 + c0];
      bf16x8 b1 = *(const bf16x8*)&msb[(16 + l)*256 + c0];
      S0 = __builtin_amdgcn_mfma_f32_16x16x32_bf16(qa[kk], b0, S0, 0, 0, 0);
      S1 = __builtin_amdgcn_mfma_f32_16x16x32_bf16(qa[kk], b1, S1, 0, 0, 0);
    }

    // ---- exp / top-2 track / stage P ----
    #pragma unroll
    for (int c = 0; c < 2; ++c){
      int slot = i0 + 16*c + l;
      #pragma unroll
      for (int reg = 0; reg < 4; ++reg){
        float v = (c == 0) ? S0[reg] : S1[reg];
        bool g0 = v > tv0[reg];
        bool g1 = v > tv1[reg];
        float ov0 = tv0[reg]; int oi0 = ti0[reg];
        tv1[reg] = g0 ? ov0 : (g1 ? v : tv1[reg]);
        ti1[reg] = g0 ? oi0 : (g1 ? slot : ti1[reg]);
        tv0[reg] = g0 ? v : tv0[reg];
        ti0[reg] = g0 ? slot : ti0[reg];
        unsigned short wb = f2b(__expf(v));
        dsum[reg] += b2f(wb);
        Plds[(16*w + 4*q + reg)*40 + 16*c + l] = (short)wb;
      }
    }
    SBAR_LGKM();   // P visible to all waves; staging loads stay in flight

    // ---- PV on Md[cur] ----
    bf16x8 pa = *(const bf16x8*)&Plds[(16*w + l)*40 + 8*q];
    const unsigned short* mdb = &Md[cur][0];
    #pragma unroll
    for (int ct = 0; ct < 16; ++ct){
      bf16x8 b = *(const bf16x8*)&mdb[(16*ct + l)*32 + sw2];
      accO[ct] = __builtin_amdgcn_mfma_f32_16x16x32_bf16(pa, b, accO[ct], 0, 0, 0);
    }
    SBAR_ALL();    // next tile's staging complete everywhere; P reads done
  }

  #pragma unroll
  for (int reg = 0; reg < 4; ++reg){
    float s = dsum[reg];
    s += __shfl_xor(s, 1, 64); s += __shfl_xor(s, 2, 64);
    s += __shfl_xor(s, 4, 64); s += __shfl_xor(s, 8, 64);
    if (l == 0) atomicAdd(&denom[row0 + 16*w + 4*q + reg], s);
  }
  #pragma unroll
  for (int reg = 0; reg < 4; ++reg){
    int row = row0 + 16*w + 4*q + reg;
    size_t base = (((size_t)row*NCG + cg)*16 + l)*2;
    float2* S2 = (float2*)sst;
    S2[base + 0] = make_float2(tv0[reg], __int_as_float(ti0[reg]));
    S2[base + 1] = make_float2(tv1[reg], __int_as_float(ti1[reg]));
  }
  #pragma unroll
  for (int ct = 0; ct < 16; ++ct){
    #pragma unroll
    for (int reg = 0; reg < 4; ++reg){
      int row = row0 + 16*w + 4*q + reg;
      atomicAdd(&outc[(size_t)row*DIM + 16*ct + l], accO[ct][reg]);
    }
  }
}

// ---------------- finish: exact-fp32 argmax recheck + normalize + topk gather ----------------
__global__ __launch_bounds__(256) void k_finish(const float* __restrict__ sst, const float* __restrict__ denom,
                                                const float* __restrict__ qn, const float* __restrict__ rn,
                                                const float* __restrict__ mem,
                                                float* __restrict__ outc, float* __restrict__ outk){
  int row = blockIdx.x, t = threadIdx.x;
  __shared__ float red[256];
  __shared__ int cnt;
  __shared__ int cidx[128];
  __shared__ float csim[128];
  __shared__ int bestIdx;
  const float2* S = (const float2*)sst + (size_t)row*NCG*16*2;
  float2 e[8];
  float lmax = -1e30f;
  #pragma unroll
  for (int k = 0; k < 8; ++k){ e[k] = S[t*8 + k]; lmax = fmaxf(lmax, e[k].x); }
  red[t] = lmax;
  __syncthreads();
  for (int s = 128; s > 0; s >>= 1){
    if (t < s) red[t] = fmaxf(red[t], red[t+s]);
    __syncthreads();
  }
  float M = red[0];
  if (t == 0) cnt = 0;
  __syncthreads();
  #pragma unroll
  for (int k = 0; k < 8; ++k){
    if (e[k].x >= M - DELTA){
      int p = atomicAdd(&cnt, 1);
      if (p < 128) cidx[p] = __float_as_int(e[k].y);
    }
  }
  __syncthreads();
  int n = min(cnt, 128);
  int wv = t >> 6, ln = t & 63;
  for (int ci = wv; ci < n; ci += 4){
    int slot = cidx[ci];
    float4 a = ((const float4*)&qn[(size_t)row*DIM])[ln];
    float4 b = ((const float4*)&mem[(size_t)slot*DIM])[ln];
    float s = a.x*b.x + a.y*b.y + a.z*b.z + a.w*b.w;
    #pragma unroll
    for (int off = 32; off > 0; off >>= 1) s += __shfl_xor(s, off, 64);
    if (ln == 0) csim[ci] = s * rn[slot];
  }
  __syncthreads();
  if (t == 0){
    float bv = -1e30f; int bi = 0x7fffffff;
    for (int i = 0; i < n; ++i){
      float v = csim[i]; int id = cidx[i];
      if (v > bv || (v == bv && id < bi)){ bv = v; bi = id; }
    }
    bestIdx = bi;
  }
  __syncthreads();
  float inv = 1.0f / denom[row];
  outc[(size_t)row*DIM + t] *= inv;
  outk[(size_t)row*DIM + t] = mem[(size_t)bestIdx*DIM + t];
}

// ---------------- new_mem via MFMA: out = mem*erase + W^T @ value ----------------
// Double-buffered LDS staging (simfused pattern): per 32-batch chunk c, DMA
// 16 KB of V^T + 4 KB of W via global_load_lds (contiguous, shared by all 4
// waves). Kills the per-wave 256KB scattered VT re-read that left the old
// kernel latency-bound at 4% on every pipe.
__global__ __launch_bounds__(256, 4) void k_newmem(const float* __restrict__ mem,
                                                const unsigned short* __restrict__ VT2,
                                                const unsigned short* __restrict__ WFT2,
                                                float* __restrict__ outm){
  __shared__ __align__(16) unsigned short VB[2][256*32];  // 16 KB per buf
  __shared__ __align__(16) unsigned short WB[2][64*32];   // 4 KB per buf

  int t = threadIdx.x;
  int i0 = blockIdx.x * 64;
  int w = t >> 6;
  int lane = t & 63;
  int l = lane & 15, q = lane >> 4;

  const char* vbase = (const char*)VT2 + (size_t)w*4096 + (size_t)lane*16;
  const char* wbase = (const char*)WFT2 + (size_t)blockIdx.x*65536 + (size_t)w*1024 + (size_t)lane*16;

  auto STAGE = [&](int c, int buf){
    #pragma unroll
    for (int j = 0; j < 4; ++j)
      gl16(vbase + (size_t)c*16384 + (size_t)j*1024, &VB[buf][w*2048 + j*512]);
    gl16(wbase + (size_t)c*4096, &WB[buf][w*512]);
  };

  f32x4 accO[16];
  #pragma unroll
  for (int c = 0; c < 16; ++c) accO[c] = (f32x4){0.f,0.f,0.f,0.f};
  float epl = 1.0f;

  STAGE(0, 0);
  SBAR_ALL();

  int sw2 = (q ^ ((l >> 1) & 3)) * 8;

  #pragma unroll 1
  for (int c = 0; c < 16; ++c){
    int cur = c & 1;
    if (c + 1 < 16) STAGE(c + 1, cur ^ 1);
    bf16x8 af = *(const bf16x8*)&WB[cur][(16*w + l)*32 + sw2];
    #pragma unroll
    for (int j = 0; j < 8; ++j)
      epl *= (1.0f - 0.5f*b2f((unsigned short)af[j]));
    #pragma unroll
    for (int ct = 0; ct < 16; ++ct){
      bf16x8 bfg = *(const bf16x8*)&VB[cur][(16*ct + l)*32 + sw2];
      accO[ct] = __builtin_amdgcn_mfma_f32_16x16x32_bf16(af, bfg, accO[ct], 0, 0, 0);
    }
    SBAR_ALL();   // next chunk staged everywhere; cur buffer free for reuse
  }

  // complete erase product across the 4 q-groups (same l => same slot)
  epl *= __shfl_xor(epl, 16, 64);
  epl *= __shfl_xor(epl, 32, 64);

  #pragma unroll
  for (int reg = 0; reg < 4; ++reg){
    int so = i0 + 16*w + 4*q + reg;
    float e = __shfl(epl, 4*q + reg, 64);   // lane (l'=4q+reg, q'=0) holds it
    #pragma unroll
    for (int ct = 0; ct < 16; ++ct){
      int d = 16*ct + l;
      outm[(size_t)so*DIM + d] = mem[(size_t)so*DIM + d]*e + accO[ct][reg];
    }
  }
}

extern "C" void kernel_launch(void* const* d_in, const int* in_sizes, int n_in,
                              void* d_out, int out_size, void* d_ws, size_t ws_size,
                              hipStream_t stream){
  const float* mem  = (const float*)d_in[0];
  const float* qry  = (const float*)d_in[1];
  const float* val  = (const float*)d_in[2];
  const float* prev = (const float*)d_in[3];
  const float* sw   = (const float*)d_in[4];
  // d_in[5] = k : unused — w_topk is analytically one-hot at argmax(sim) for any k
  float* out = (float*)d_out;
  float* ws  = (float*)d_ws;

  float* qn   = ws + WS_QN;
  float* rn   = ws + WS_RN;
  float* wst  = ws + WS_WST;
  float* den  = ws + WS_DEN;
  float* sst  = ws + WS_SST;
  unsigned short* VT = (unsigned short*)(ws + WS_VT);
  unsigned short* MN = (unsigned short*)(ws + WS_MN);
  unsigned short* MT = (unsigned short*)(ws + WS_MT);
  unsigned short* WFT = MN;   // aliases MN+MT (64 MB), dead after k_simfused

  float* out_content = out;
  float* out_topk    = out + BATCH*DIM;
  float* out_newmem  = out + 2*BATCH*DIM;

  hipMemsetAsync(out_content, 0, BATCH*DIM*sizeof(float), stream);
  hipMemsetAsync(den, 0, BATCH*sizeof(float), stream);
  hipLaunchKernelGGL(k_qnorm,   dim3(BATCH),       dim3(DIM), 0, stream, qry, qn);
  hipLaunchKernelGGL(k_mnprep,  dim3(NSLOTS/64),   dim3(256), 0, stream, mem, rn, MN);
  hipLaunchKernelGGL(k_mtprep,  dim3((NSLOTS/64)*4), dim3(256), 0, stream, mem, MT);
  hipLaunchKernelGGL(k_prep,    dim3(32),          dim3(256), 0, stream, val, VT);
  hipLaunchKernelGGL(k_wstats,  dim3(BATCH),       dim3(256), 0, stream, prev, sw, wst);
  hipLaunchKernelGGL(k_simfused,dim3(NCG, NROWG),  dim3(256), 0, stream, qn, MN, MT, out_content, den, sst);
  hipLaunchKernelGGL(k_wft,     dim3((NSLOTS/64)*(BATCH/64)), dim3(256), 0, stream, prev, sw, wst, WFT);
  hipLaunchKernelGGL(k_finish,  dim3(BATCH),       dim3(256), 0, stream, sst, den, qn, rn, mem, out_content, out_topk);
  hipLaunchKernelGGL(k_newmem,  dim3(NSLOTS/64),   dim3(256), 0, stream, mem, VT, WFT, out_newmem);
}

// Round 5
// 495.124 us; speedup vs baseline: 1.2553x; 1.0556x over previous
//
#include <hip/hip_runtime.h>
#include <math.h>

#define BATCH   512
#define NSLOTS  65536
#define DIM     256

#define RB      64            // rows per block (simfused)
#define NROWG   (BATCH/RB)    // 8
#define NCG     64            // column groups (simfused)
#define CPG     (NSLOTS/NCG)  // 1024 slots per group
#define ST      32            // slot tile
#define NTILES  (CPG/ST)      // 32
#define DELTA   0.009f        // 2x worst-case bf16-input sim perturbation

// workspace layout (float offsets)
#define WS_QN   0
#define WS_RN   (WS_QN + BATCH*DIM)            // +131072
#define WS_WST  (WS_RN + NSLOTS)               // +65536
#define WS_DEN  (WS_WST + BATCH*4)             // +2048
#define WS_ZS   (WS_DEN + BATCH)               // +512 : sharp-sum per batch
#define WS_ZZ   (WS_ZS + BATCH)                // +512 : Z per batch
#define WS_SST  (WS_ZZ + BATCH)                // +512 : [512][64 cg][16 lanes][2] float2 = 8 MB
#define WS_VT   (WS_SST + BATCH*NCG*16*4)      // +2097152 : value^T bf16, chunked [16 c][256 d][32 b], 256 KB
#define WS_MN   (WS_VT + (BATCH*DIM)/2)        // +65536 : normalized-bf16 memory, chunk-swizzled, 32 MB
#define WS_MT   (WS_MN + ((size_t)NSLOTS*DIM)/2) // +8388608 : bf16 memory^T, chunk-swizzled, 32 MB
// WFT2 (wf bf16 [1024 sblk][16 c][64 s][32 b] = 64 MB) aliases MN+MT (dead after k_simfused)
// total ~76.6 MB

typedef __attribute__((ext_vector_type(8))) short bf16x8;
typedef __attribute__((ext_vector_type(4))) float f32x4;

__device__ inline unsigned short f2b(float x){   // fp32 -> bf16 RNE
  unsigned u = __float_as_uint(x);
  unsigned r = u + 0x7FFFu + ((u >> 16) & 1u);
  return (unsigned short)(r >> 16);
}
__device__ inline float b2f(unsigned short b){
  return __uint_as_float(((unsigned)b) << 16);
}

__device__ __forceinline__ void gl16(const void* g, void* l){
  __builtin_amdgcn_global_load_lds(
      (__attribute__((address_space(1))) void*)g,
      (__attribute__((address_space(3))) void*)l, 16, 0, 0);
}

#define SBAR_LGKM() do{ asm volatile("s_waitcnt lgkmcnt(0)" ::: "memory"); \
                        __builtin_amdgcn_s_barrier();                      \
                        asm volatile("" ::: "memory"); }while(0)
#define SBAR_ALL()  do{ asm volatile("s_waitcnt vmcnt(0) lgkmcnt(0)" ::: "memory"); \
                        __builtin_amdgcn_s_barrier();                               \
                        asm volatile("" ::: "memory"); }while(0)

// ---------------- query L2 norm ----------------
__global__ __launch_bounds__(256) void k_qnorm(const float* __restrict__ q, float* __restrict__ qn){
  int b = blockIdx.x, t = threadIdx.x;
  float v = q[b*DIM + t];
  __shared__ float red[256];
  red[t] = v*v;
  __syncthreads();
  for (int s = 128; s > 0; s >>= 1){
    if (t < s) red[t] += red[t+s];
    __syncthreads();
  }
  float n = fmaxf(sqrtf(red[0]), 1e-12f);
  qn[b*DIM + t] = v / n;
}

// ---------------- prep: row norms + normalized-bf16 memory, chunk-swizzled ----------------
// MN_swz[s][chunk pos] : chunk c (8 dims, 16B) of slot s stored at position c ^ (s&7).
__global__ __launch_bounds__(256) void k_mnprep(const float* __restrict__ mem,
                                                float* __restrict__ rn,
                                                unsigned short* __restrict__ MN){
  __shared__ float rns[64];
  int t = threadIdx.x;
  int s0 = blockIdx.x * 64;
  int w = t >> 6, ln = t & 63;
  #pragma unroll
  for (int it = 0; it < 16; ++it){
    int r = it*4 + w;
    float4 v = ((const float4*)(mem + (size_t)(s0 + r)*DIM))[ln];
    float s = v.x*v.x + v.y*v.y + v.z*v.z + v.w*v.w;
    #pragma unroll
    for (int off = 32; off > 0; off >>= 1) s += __shfl_xor(s, off, 64);
    if (ln == 0){
      float inv = 1.0f / fmaxf(sqrtf(s), 1e-12f);
      rns[r] = inv; rn[s0 + r] = inv;
    }
  }
  __syncthreads();
  #pragma unroll
  for (int j = 0; j < 8; ++j){
    int id = j*256 + t;
    int r = id >> 5;        // local slot 0..63
    int c = id & 31;        // chunk 0..31
    float inv = rns[r];
    const float4* p = (const float4*)(mem + (size_t)(s0 + r)*DIM + c*8);
    float4 a = p[0], b = p[1];
    bf16x8 o;
    o[0]=(short)f2b(a.x*inv); o[1]=(short)f2b(a.y*inv); o[2]=(short)f2b(a.z*inv); o[3]=(short)f2b(a.w*inv);
    o[4]=(short)f2b(b.x*inv); o[5]=(short)f2b(b.y*inv); o[6]=(short)f2b(b.z*inv); o[7]=(short)f2b(b.w*inv);
    *(bf16x8*)&MN[(size_t)(s0 + r)*DIM + ((c ^ (r & 7))*8)] = o;
  }
}

// ---------------- prep: bf16 memory^T, chunk-swizzled ----------------
// MT_swz[d][...] : within each aligned 32-slot block, chunk p (8 slots) stored at p ^ ((d>>1)&3).
__global__ __launch_bounds__(256) void k_mtprep(const float* __restrict__ mem, unsigned short* __restrict__ MT){
  __shared__ __align__(16) unsigned short tile[64][68];
  int sb = (blockIdx.x >> 2)*64, dd = (blockIdx.x & 3)*64;
  int t = threadIdx.x;
  int w = t >> 6, ln = t & 63;
  #pragma unroll
  for (int k = 0; k < 4; ++k){
    int sl = w*16 + k*4 + (ln >> 4);
    int doff = (ln & 15)*4;
    float4 f = *(const float4*)&mem[(size_t)(sb + sl)*DIM + dd + doff];
    tile[doff+0][sl] = f2b(f.x);
    tile[doff+1][sl] = f2b(f.y);
    tile[doff+2][sl] = f2b(f.z);
    tile[doff+3][sl] = f2b(f.w);
  }
  __syncthreads();
  #pragma unroll
  for (int k = 0; k < 4; ++k){
    int dl = w*16 + k*4 + (ln >> 4);
    int boff = (ln & 15)*4;
    int B = boff >> 5;
    int p = (boff >> 3) & 3;
    int pp = p ^ ((dl >> 1) & 3);          // (d>>1)&3 == (dl>>1)&3 (dd % 64 == 0)
    int off = B*32 + pp*8 + (boff & 7);
    *(short4*)&MT[(size_t)(dd + dl)*NSLOTS + sb + off] = *(const short4*)&tile[dl][boff];
  }
}

// ---------------- value^T bf16 prep: VT2[c][d][b-local], swizzled ----------------
// Chunk c (32 batches) stored contiguously (16 KB); within it row d, 8-batch
// group p stored at p ^ ((d>>1)&3)  — matches k_newmem's LDS B-frag read.
__global__ __launch_bounds__(256) void k_prep(const float* __restrict__ val, unsigned short* __restrict__ VT){
  __shared__ __align__(16) unsigned short tile[64][68];
  int bb = (blockIdx.x >> 2)*64, dd = (blockIdx.x & 3)*64;
  int t = threadIdx.x;
  int w = t >> 6, ln = t & 63;
  #pragma unroll
  for (int k = 0; k < 4; ++k){
    int bl = w*16 + k*4 + (ln >> 4);
    int doff = (ln & 15)*4;
    float4 f = *(const float4*)&val[(size_t)(bb + bl)*DIM + dd + doff];
    tile[doff+0][bl] = f2b(f.x);
    tile[doff+1][bl] = f2b(f.y);
    tile[doff+2][bl] = f2b(f.z);
    tile[doff+3][bl] = f2b(f.w);
  }
  __syncthreads();
  #pragma unroll
  for (int k = 0; k < 4; ++k){
    int dl = w*16 + k*4 + (ln >> 4);
    int boff = (ln & 15)*4;
    int c  = (bb + boff) >> 5;
    int p  = (boff >> 3) & 3;
    int pp = p ^ ((dl >> 1) & 3);
    size_t addr = (size_t)c*8192 + (size_t)(dd + dl)*32 + pp*8 + (boff & 7);
    *(short4*)&VT[addr] = *(const short4*)&tile[dl][boff];
  }
}

// ---------------- write-weight stats, pass 1: per-batch sharp-sum (16-way split) ----------------
__global__ __launch_bounds__(256) void k_ws1(const float* __restrict__ prev, const float* __restrict__ sw,
                                             float* __restrict__ zs){
  int blk = blockIdx.x;
  int b = blk >> 4, ch = blk & 15;
  int t = threadIdx.x;
  int w = t >> 6, lane = t & 63;
  float s0 = sw[0], s1 = sw[1], s2 = sw[2];
  const float* p = prev + (size_t)b*NSLOTS;
  const float4* p4 = (const float4*)p;
  float lsum = 0.f;
  #pragma unroll
  for (int k = 0; k < 4; ++k){
    int i4 = ch*1024 + k*256 + t;
    float4 f = p4[i4];
    float lft = (i4 > 0) ? p[4*i4 - 1] : 0.f;
    float rgt = (i4 < NSLOTS/4 - 1) ? p[4*i4 + 4] : 0.f;
    float sh0 = s0*lft + s1*f.x + s2*f.y;
    float sh1 = s0*f.x + s1*f.y + s2*f.z;
    float sh2 = s0*f.y + s1*f.z + s2*f.w;
    float sh3 = s0*f.z + s1*f.w + s2*rgt;
    lsum += sh0*sqrtf(sh0) + sh1*sqrtf(sh1) + sh2*sqrtf(sh2) + sh3*sqrtf(sh3);
  }
  #pragma unroll
  for (int off = 32; off > 0; off >>= 1) lsum += __shfl_xor(lsum, off, 64);
  __shared__ float wsum[4];
  if (lane == 0) wsum[w] = lsum;
  __syncthreads();
  if (t == 0) atomicAdd(&zs[b], wsum[0] + wsum[1] + wsum[2] + wsum[3]);
}

// ---------------- write-weight stats, pass 2: per-batch Z (prev L3-resident) ----------------
__global__ __launch_bounds__(256) void k_ws2(const float* __restrict__ prev, const float* __restrict__ sw,
                                             const float* __restrict__ zs, float* __restrict__ zz){
  int blk = blockIdx.x;
  int b = blk >> 4, ch = blk & 15;
  int t = threadIdx.x;
  int w = t >> 6, lane = t & 63;
  float s0 = sw[0], s1 = sw[1], s2 = sw[2];
  float inv_d = 1.0f / (zs[b] + 1e-8f);
  const float* p = prev + (size_t)b*NSLOTS;
  const float4* p4 = (const float4*)p;
  float lz = 0.f;
  #pragma unroll
  for (int k = 0; k < 4; ++k){
    int i4 = ch*1024 + k*256 + t;
    float4 f = p4[i4];
    float lft = (i4 > 0) ? p[4*i4 - 1] : 0.f;
    float rgt = (i4 < NSLOTS/4 - 1) ? p[4*i4 + 4] : 0.f;
    float sh0 = s0*lft + s1*f.x + s2*f.y;
    float sh1 = s0*f.x + s1*f.y + s2*f.z;
    float sh2 = s0*f.y + s1*f.z + s2*f.w;
    float sh3 = s0*f.z + s1*f.w + s2*rgt;
    lz += __expf(sh0*sqrtf(sh0)*inv_d) + __expf(sh1*sqrtf(sh1)*inv_d)
        + __expf(sh2*sqrtf(sh2)*inv_d) + __expf(sh3*sqrtf(sh3)*inv_d);
  }
  #pragma unroll
  for (int off = 32; off > 0; off >>= 1) lz += __shfl_xor(lz, off, 64);
  __shared__ float wsum[4];
  if (lane == 0) wsum[w] = lz;
  __syncthreads();
  if (t == 0) atomicAdd(&zz[b], wsum[0] + wsum[1] + wsum[2] + wsum[3]);
}

// ---------------- finalize stats: wst[b] = {inv_d, invZ} ----------------
__global__ __launch_bounds__(256) void k_invd(const float* __restrict__ zs, const float* __restrict__ zz,
                                              float* __restrict__ wst){
  int b = blockIdx.x*256 + threadIdx.x;
  float4 o;
  o.x = 1.0f / (zs[b] + 1e-8f);
  o.y = 1.0f / zz[b];
  o.z = 0.f; o.w = 0.f;
  ((float4*)wst)[b] = o;
}

// ---------------- wf: WFT2[sblk][c][slot-local][b-local], swizzled ----------------
// Reads prev batch-major (coalesced), computes wf, LDS-transposes 64x64 tiles,
// writes the tiled layout k_newmem stages from: slot tile sblk, batch chunk c
// (32 b) contiguous 4 KB; within it row s, 8-batch group p at p ^ ((s>>1)&3).
__global__ __launch_bounds__(256) void k_wft(const float* __restrict__ prev, const float* __restrict__ sw,
                                             const float* __restrict__ wst, unsigned short* __restrict__ WFT){
  __shared__ __align__(16) unsigned short T[64][72];
  int bs = ((int)blockIdx.x & 7) * 64;       // batch tile
  int ss = ((int)blockIdx.x >> 3) * 64;      // slot tile
  int t = threadIdx.x;
  float s0 = sw[0], s1 = sw[1], s2 = sw[2];
  int rr = t >> 4;          // 0..15 batch row within pass
  int cc = t & 15;          // float4 col (slot dim)
  #pragma unroll
  for (int pass = 0; pass < 4; ++pass){
    int bl = pass*16 + rr;
    int b = bs + bl;
    const float* p = prev + (size_t)b*NSLOTS + ss;
    float2 st = *(const float2*)&wst[b*4];   // {inv_d, invZ}
    int s = cc*4;
    float4 f = *(const float4*)(p + s);
    int gs = ss + s;
    float lft = (gs > 0) ? p[s-1] : 0.f;
    float rgt = (gs + 4 < NSLOTS) ? p[s+4] : 0.f;
    float sh0 = s0*lft + s1*f.x + s2*f.y;
    float sh1 = s0*f.x + s1*f.y + s2*f.z;
    float sh2 = s0*f.y + s1*f.z + s2*f.w;
    float sh3 = s0*f.z + s1*f.w + s2*rgt;
    T[s+0][bl] = f2b(__expf(sh0*sqrtf(sh0)*st.x)*st.y);
    T[s+1][bl] = f2b(__expf(sh1*sqrtf(sh1)*st.x)*st.y);
    T[s+2][bl] = f2b(__expf(sh2*sqrtf(sh2)*st.x)*st.y);
    T[s+3][bl] = f2b(__expf(sh3*sqrtf(sh3)*st.x)*st.y);
  }
  __syncthreads();
  int sr = t >> 3;          // 0..31 slot row
  int ch = t & 7;           // 16B chunk within the 128B row (= 8 batches)
  #pragma unroll
  for (int k = 0; k < 2; ++k){
    int row = k*32 + sr;
    int c  = (bs >> 5) + (ch >> 2);          // global 32-batch chunk
    int pp = (ch & 3) ^ ((row >> 1) & 3);
    size_t addr = (size_t)(ss >> 6)*32768 + (size_t)c*2048 + (size_t)row*32 + pp*8;
    *(bf16x8*)&WFT[addr] = *(const bf16x8*)&T[row][ch*8];
  }
}

// ---------------- MFMA fused sim pass: async-staged, double-buffered, swizzled LDS ----------------
// Ms LDS [32][256] bf16 linear; content pre-swizzled in MN (chunk c at c^(row&7)).
// Md LDS [256][32] bf16 linear; content pre-swizzled in MT (chunk p at p^((d>>1)&3)).
__global__ __launch_bounds__(256, 2) void k_simfused(
    const float* __restrict__ qn,
    const unsigned short* __restrict__ MN,
    const unsigned short* __restrict__ MT,
    float* __restrict__ outc, float* __restrict__ denom, float* __restrict__ sst)
{
  __shared__ __align__(16) unsigned short Ms[2][32*256];
  __shared__ __align__(16) unsigned short Md[2][256*32];
  __shared__ __align__(16) unsigned short Plds[64*40];

  int cg = blockIdx.x, rg = blockIdx.y;     // swapped grid: same-cg blocks share an XCD L2
  int t = threadIdx.x;
  int w = t >> 6;
  int lane = t & 63;
  int l = lane & 15;
  int q = lane >> 4;
  int row0 = rg * RB;

  bf16x8 qa[8];
  {
    int qrow = row0 + 16*w + l;
    #pragma unroll
    for (int kk = 0; kk < 8; ++kk){
      const float4* qp = (const float4*)&qn[(size_t)qrow*DIM + 32*kk + 8*q];
      float4 a0 = qp[0], a1 = qp[1];
      bf16x8 v;
      v[0]=(short)f2b(a0.x); v[1]=(short)f2b(a0.y); v[2]=(short)f2b(a0.z); v[3]=(short)f2b(a0.w);
      v[4]=(short)f2b(a1.x); v[5]=(short)f2b(a1.y); v[6]=(short)f2b(a1.z); v[7]=(short)f2b(a1.w);
      qa[kk] = v;
    }
  }

  // per-lane staging source bases (tile 0)
  const char* msP = (const char*)MN + (size_t)cg*CPG*512 + (size_t)w*4096 + (size_t)lane*16;
  const char* mtP = (const char*)MT + (size_t)(w*64 + (lane>>2))*((size_t)NSLOTS*2)
                                    + (size_t)cg*CPG*2 + (size_t)(lane&3)*16;

  auto STAGE = [&](int tl, int buf){
    size_t mso = (size_t)tl*16384;   // 32 rows * 512 B
    size_t mto = (size_t)tl*64;      // 32 slots * 2 B
    #pragma unroll
    for (int j = 0; j < 4; ++j)
      gl16(msP + mso + (size_t)j*1024, &Ms[buf][w*2048 + j*512]);
    #pragma unroll
    for (int j = 0; j < 4; ++j)
      gl16(mtP + mto + (size_t)j*2097152, &Md[buf][w*2048 + j*512]);
  };

  f32x4 accO[16];
  #pragma unroll
  for (int c = 0; c < 16; ++c) accO[c] = (f32x4){0.f,0.f,0.f,0.f};

  float dsum[4] = {0.f,0.f,0.f,0.f};
  float tv0[4] = {-1e30f,-1e30f,-1e30f,-1e30f}, tv1[4] = {-1e30f,-1e30f,-1e30f,-1e30f};
  int   ti0[4] = {0,0,0,0}, ti1[4] = {0,0,0,0};

  STAGE(0, 0);
  SBAR_ALL();

  int r7 = l & 7;
  int sw2 = (q ^ ((l >> 1) & 3)) * 8;

  for (int tile = 0; tile < NTILES; ++tile){
    int cur = tile & 1;
    if (tile + 1 < NTILES) STAGE(tile + 1, cur ^ 1);
    int i0 = cg*CPG + tile*ST;

    // ---- QK^T on Ms[cur] ----
    const unsigned short* msb = &Ms[cur][0];
    f32x4 S0 = (f32x4){0.f,0.f,0.f,0.f}, S1 = (f32x4){0.f,0.f,0.f,0.f};
    #pragma unroll
    for (int kk = 0; kk < 8; ++kk){
      int c0 = ((4*kk + q) ^ r7) * 8;
      bf16x8 b0 = *(const bf16x8*)&msb[(l     )*256 + c0];
      bf16x8 b1 = *(const bf16x8*)&msb[(16 + l)*256 + c0];
      S0 = __builtin_amdgcn_mfma_f32_16x16x32_bf16(qa[kk], b0, S0, 0, 0, 0);
      S1 = __builtin_amdgcn_mfma_f32_16x16x32_bf16(qa[kk], b1, S1, 0, 0, 0);
    }

    // ---- exp / top-2 track / stage P ----
    #pragma unroll
    for (int c = 0; c < 2; ++c){
      int slot = i0 + 16*c + l;
      #pragma unroll
      for (int reg = 0; reg < 4; ++reg){
        float v = (c == 0) ? S0[reg] : S1[reg];
        bool g0 = v > tv0[reg];
        bool g1 = v > tv1[reg];
        float ov0 = tv0[reg]; int oi0 = ti0[reg];
        tv1[reg] = g0 ? ov0 : (g1 ? v : tv1[reg]);
        ti1[reg] = g0 ? oi0 : (g1 ? slot : ti1[reg]);
        tv0[reg] = g0 ? v : tv0[reg];
        ti0[reg] = g0 ? slot : ti0[reg];
        unsigned short wb = f2b(__expf(v));
        dsum[reg] += b2f(wb);
        Plds[(16*w + 4*q + reg)*40 + 16*c + l] = (short)wb;
      }
    }
    SBAR_LGKM();   // P visible to all waves; staging loads stay in flight

    // ---- PV on Md[cur] ----
    bf16x8 pa = *(const bf16x8*)&Plds[(16*w + l)*40 + 8*q];
    const unsigned short* mdb = &Md[cur][0];
    #pragma unroll
    for (int ct = 0; ct < 16; ++ct){
      bf16x8 b = *(const bf16x8*)&mdb[(16*ct + l)*32 + sw2];
      accO[ct] = __builtin_amdgcn_mfma_f32_16x16x32_bf16(pa, b, accO[ct], 0, 0, 0);
    }
    SBAR_ALL();    // next tile's staging complete everywhere; P reads done
  }

  #pragma unroll
  for (int reg = 0; reg < 4; ++reg){
    float s = dsum[reg];
    s += __shfl_xor(s, 1, 64); s += __shfl_xor(s, 2, 64);
    s += __shfl_xor(s, 4, 64); s += __shfl_xor(s, 8, 64);
    if (l == 0) atomicAdd(&denom[row0 + 16*w + 4*q + reg], s);
  }
  #pragma unroll
  for (int reg = 0; reg < 4; ++reg){
    int row = row0 + 16*w + 4*q + reg;
    size_t base = (((size_t)row*NCG + cg)*16 + l)*2;
    float2* S2 = (float2*)sst;
    S2[base + 0] = make_float2(tv0[reg], __int_as_float(ti0[reg]));
    S2[base + 1] = make_float2(tv1[reg], __int_as_float(ti1[reg]));
  }
  #pragma unroll
  for (int ct = 0; ct < 16; ++ct){
    #pragma unroll
    for (int reg = 0; reg < 4; ++reg){
      int row = row0 + 16*w + 4*q + reg;
      atomicAdd(&outc[(size_t)row*DIM + 16*ct + l], accO[ct][reg]);
    }
  }
}

// ---------------- finish: exact-fp32 argmax recheck + normalize + topk gather ----------------
__global__ __launch_bounds__(256) void k_finish(const float* __restrict__ sst, const float* __restrict__ denom,
                                                const float* __restrict__ qn, const float* __restrict__ rn,
                                                const float* __restrict__ mem,
                                                float* __restrict__ outc, float* __restrict__ outk){
  int row = blockIdx.x, t = threadIdx.x;
  __shared__ float red[256];
  __shared__ int cnt;
  __shared__ int cidx[128];
  __shared__ float csim[128];
  __shared__ int bestIdx;
  const float2* S = (const float2*)sst + (size_t)row*NCG*16*2;
  float2 e[8];
  float lmax = -1e30f;
  #pragma unroll
  for (int k = 0; k < 8; ++k){ e[k] = S[t*8 + k]; lmax = fmaxf(lmax, e[k].x); }
  red[t] = lmax;
  __syncthreads();
  for (int s = 128; s > 0; s >>= 1){
    if (t < s) red[t] = fmaxf(red[t], red[t+s]);
    __syncthreads();
  }
  float M = red[0];
  if (t == 0) cnt = 0;
  __syncthreads();
  #pragma unroll
  for (int k = 0; k < 8; ++k){
    if (e[k].x >= M - DELTA){
      int p = atomicAdd(&cnt, 1);
      if (p < 128) cidx[p] = __float_as_int(e[k].y);
    }
  }
  __syncthreads();
  int n = min(cnt, 128);
  int wv = t >> 6, ln = t & 63;
  for (int ci = wv; ci < n; ci += 4){
    int slot = cidx[ci];
    float4 a = ((const float4*)&qn[(size_t)row*DIM])[ln];
    float4 b = ((const float4*)&mem[(size_t)slot*DIM])[ln];
    float s = a.x*b.x + a.y*b.y + a.z*b.z + a.w*b.w;
    #pragma unroll
    for (int off = 32; off > 0; off >>= 1) s += __shfl_xor(s, off, 64);
    if (ln == 0) csim[ci] = s * rn[slot];
  }
  __syncthreads();
  if (t == 0){
    float bv = -1e30f; int bi = 0x7fffffff;
    for (int i = 0; i < n; ++i){
      float v = csim[i]; int id = cidx[i];
      if (v > bv || (v == bv && id < bi)){ bv = v; bi = id; }
    }
    bestIdx = bi;
  }
  __syncthreads();
  float inv = 1.0f / denom[row];
  outc[(size_t)row*DIM + t] *= inv;
  outk[(size_t)row*DIM + t] = mem[(size_t)bestIdx*DIM + t];
}

// ---------------- new_mem via MFMA: out = mem*erase + W^T @ value ----------------
// Double-buffered LDS staging (simfused pattern): per 32-batch chunk c, DMA
// 16 KB of V^T + 4 KB of W via global_load_lds (contiguous, shared by all 4
// waves). Kills the per-wave 256KB scattered VT re-read that left the old
// kernel latency-bound at 4% on every pipe.
__global__ __launch_bounds__(256, 4) void k_newmem(const float* __restrict__ mem,
                                                const unsigned short* __restrict__ VT2,
                                                const unsigned short* __restrict__ WFT2,
                                                float* __restrict__ outm){
  __shared__ __align__(16) unsigned short VB[2][256*32];  // 16 KB per buf
  __shared__ __align__(16) unsigned short WB[2][64*32];   // 4 KB per buf

  int t = threadIdx.x;
  int i0 = blockIdx.x * 64;
  int w = t >> 6;
  int lane = t & 63;
  int l = lane & 15, q = lane >> 4;

  const char* vbase = (const char*)VT2 + (size_t)w*4096 + (size_t)lane*16;
  const char* wbase = (const char*)WFT2 + (size_t)blockIdx.x*65536 + (size_t)w*1024 + (size_t)lane*16;

  auto STAGE = [&](int c, int buf){
    #pragma unroll
    for (int j = 0; j < 4; ++j)
      gl16(vbase + (size_t)c*16384 + (size_t)j*1024, &VB[buf][w*2048 + j*512]);
    gl16(wbase + (size_t)c*4096, &WB[buf][w*512]);
  };

  f32x4 accO[16];
  #pragma unroll
  for (int c = 0; c < 16; ++c) accO[c] = (f32x4){0.f,0.f,0.f,0.f};
  float epl = 1.0f;

  STAGE(0, 0);
  SBAR_ALL();

  int sw2 = (q ^ ((l >> 1) & 3)) * 8;

  #pragma unroll 1
  for (int c = 0; c < 16; ++c){
    int cur = c & 1;
    if (c + 1 < 16) STAGE(c + 1, cur ^ 1);
    bf16x8 af = *(const bf16x8*)&WB[cur][(16*w + l)*32 + sw2];
    #pragma unroll
    for (int j = 0; j < 8; ++j)
      epl *= (1.0f - 0.5f*b2f((unsigned short)af[j]));
    #pragma unroll
    for (int ct = 0; ct < 16; ++ct){
      bf16x8 bfg = *(const bf16x8*)&VB[cur][(16*ct + l)*32 + sw2];
      accO[ct] = __builtin_amdgcn_mfma_f32_16x16x32_bf16(af, bfg, accO[ct], 0, 0, 0);
    }
    SBAR_ALL();   // next chunk staged everywhere; cur buffer free for reuse
  }

  // complete erase product across the 4 q-groups (same l => same slot)
  epl *= __shfl_xor(epl, 16, 64);
  epl *= __shfl_xor(epl, 32, 64);

  #pragma unroll
  for (int reg = 0; reg < 4; ++reg){
    int so = i0 + 16*w + 4*q + reg;
    float e = __shfl(epl, 4*q + reg, 64);   // lane (l'=4q+reg, q'=0) holds it
    #pragma unroll
    for (int ct = 0; ct < 16; ++ct){
      int d = 16*ct + l;
      outm[(size_t)so*DIM + d] = mem[(size_t)so*DIM + d]*e + accO[ct][reg];
    }
  }
}

extern "C" void kernel_launch(void* const* d_in, const int* in_sizes, int n_in,
                              void* d_out, int out_size, void* d_ws, size_t ws_size,
                              hipStream_t stream){
  const float* mem  = (const float*)d_in[0];
  const float* qry  = (const float*)d_in[1];
  const float* val  = (const float*)d_in[2];
  const float* prev = (const float*)d_in[3];
  const float* sw   = (const float*)d_in[4];
  // d_in[5] = k : unused — w_topk is analytically one-hot at argmax(sim) for any k
  float* out = (float*)d_out;
  float* ws  = (float*)d_ws;

  float* qn   = ws + WS_QN;
  float* rn   = ws + WS_RN;
  float* wst  = ws + WS_WST;
  float* den  = ws + WS_DEN;
  float* zs   = ws + WS_ZS;
  float* zz   = ws + WS_ZZ;
  float* sst  = ws + WS_SST;
  unsigned short* VT = (unsigned short*)(ws + WS_VT);
  unsigned short* MN = (unsigned short*)(ws + WS_MN);
  unsigned short* MT = (unsigned short*)(ws + WS_MT);
  unsigned short* WFT = MN;   // aliases MN+MT (64 MB), dead after k_simfused

  float* out_content = out;
  float* out_topk    = out + BATCH*DIM;
  float* out_newmem  = out + 2*BATCH*DIM;

  hipMemsetAsync(out_content, 0, BATCH*DIM*sizeof(float), stream);
  hipMemsetAsync(den, 0, BATCH*sizeof(float), stream);
  hipMemsetAsync(zs, 0, 2*BATCH*sizeof(float), stream);   // zs + zz (contiguous)
  hipLaunchKernelGGL(k_qnorm,   dim3(BATCH),       dim3(DIM), 0, stream, qry, qn);
  hipLaunchKernelGGL(k_mnprep,  dim3(NSLOTS/64),   dim3(256), 0, stream, mem, rn, MN);
  hipLaunchKernelGGL(k_mtprep,  dim3((NSLOTS/64)*4), dim3(256), 0, stream, mem, MT);
  hipLaunchKernelGGL(k_prep,    dim3(32),          dim3(256), 0, stream, val, VT);
  hipLaunchKernelGGL(k_ws1,     dim3(BATCH*16),    dim3(256), 0, stream, prev, sw, zs);
  hipLaunchKernelGGL(k_ws2,     dim3(BATCH*16),    dim3(256), 0, stream, prev, sw, zs, zz);
  hipLaunchKernelGGL(k_invd,    dim3(BATCH/256),   dim3(256), 0, stream, zs, zz, wst);
  hipLaunchKernelGGL(k_simfused,dim3(NCG, NROWG),  dim3(256), 0, stream, qn, MN, MT, out_content, den, sst);
  hipLaunchKernelGGL(k_wft,     dim3((NSLOTS/64)*(BATCH/64)), dim3(256), 0, stream, prev, sw, wst, WFT);
  hipLaunchKernelGGL(k_finish,  dim3(BATCH),       dim3(256), 0, stream, sst, den, qn, rn, mem, out_content, out_topk);
  hipLaunchKernelGGL(k_newmem,  dim3(NSLOTS/64),   dim3(256), 0, stream, mem, VT, WFT, out_newmem);
}